// Round 1
// baseline (80.340 us; speedup 1.0000x reference)
//
#include <hip/hip_runtime.h>
#include <math.h>

// Problem constants (match reference)
#define NTOT   5040000          // NT
#define NFORC  84000            // NF
#define NSUB_  60
#define NSTEPS (NTOT - 1)       // 5,039,999 model steps (it = 0..NT-2)

// Decomposition: block window WIN=256*60 steps; first WARM steps are redundant
// warm-up (|a|^4800 small => error ~1e-5, far under absmax budget).
#define TPB     256
#define SEGS    60              // steps per thread == NSUB (one forcing interval)
#define WIN     (TPB * SEGS)    // 15360
#define WARM    4800            // multiple of 60
#define CHUNK   (WIN - WARM)    // 10560 output steps owned per block
#define TILE    15              // LDS staging tile (4 tiles per segment)
#define NTILES  (SEGS / TILE)
#define TSTR    (TILE + 1)      // 16 float2 per row -> 32 KiB total, 5 blocks/CU

__device__ __forceinline__ float2 cmadd(float2 a, float2 p, float2 c) {
    // a*p + c, complex
    return make_float2(fmaf(a.x, p.x, fmaf(-a.y, p.y, c.x)),
                       fmaf(a.x, p.y, fmaf( a.y, p.x, c.y)));
}

__global__ __launch_bounds__(TPB, 5)
void slab_scan_kernel(const float* __restrict__ pk,
                      const float* __restrict__ TAx,
                      const float* __restrict__ TAy,
                      float* __restrict__ out)
{
    __shared__ float2 tb[TPB * TSTR];   // 32,768 B exactly: 5 blocks/CU

    const int tid  = threadIdx.x;
    const int lane = tid & 63;
    const int wv   = tid >> 6;
    const int blk  = blockIdx.x;

    // model parameters
    const float K0 = expf(pk[0]);
    const float K1 = expf(pk[1]);
    const float ar = 1.0f - 60.0f * K1;    // Re(a)
    const float ai = -60.0f * 1.0e-4f;     // Im(a) = -dt*fc
    const float s  = 60.0f * K0;           // b_t = s * TAi_t

    const int wstart = blk * CHUNK;                 // first owned output step
    const int wend   = min(wstart + CHUNK, NSTEPS); // one past last owned
    const int ws     = max(0, wstart - WARM);       // window start (mult of 60)

    // ---- forcing for this thread's 60-step segment (one interval, coalesced) ----
    const int itf = ws / NSUB_ + tid;
    const int i0  = min(itf,     NFORC - 1);
    const int i1  = min(itf + 1, NFORC - 1);
    const float x0 = TAx[i0], y0 = TAy[i0];
    const float x1 = TAx[i1], y1 = TAy[i1];
    const float cinv = s * (1.0f / 60.0f);
    const float dxs  = (x1 - x0) * cinv;   // per-substep increment of Re(b)
    const float dys  = (y1 - y0) * cinv;
    const float b0re = s * x0;             // b at aa = 0
    const float b0im = s * y0;

    // ---- pass 1: local carry over 60 steps from u = 0 ----
    float ur = 0.f, ui = 0.f;
    {
        float bre = b0re, bim = b0im;
        #pragma unroll
        for (int k = 0; k < SEGS; ++k) {
            float nr = fmaf(ar, ur, fmaf(-ai, ui, bre));
            float ni = fmaf(ar, ui, fmaf( ai, ur, bim));
            ur = nr; ui = ni;
            bre += dxs; bim += dys;
        }
    }

    // ---- apow[k] = (a^60)^(2^k), k=0..6 (0..5 intra-wave, 6 cross-wave) ----
    float2 apow[7];
    {
        double br_ = (double)ar, bi_ = (double)ai;
        double prr = 1.0, pii = 0.0;
        int e = SEGS;
        while (e) {
            if (e & 1) { double t = prr*br_ - pii*bi_; pii = prr*bi_ + pii*br_; prr = t; }
            double t = br_*br_ - bi_*bi_; bi_ = 2.0*br_*bi_; br_ = t;
            e >>= 1;
        }
        double cr = prr, ci = pii;
        #pragma unroll
        for (int k = 0; k < 7; ++k) {
            apow[k] = make_float2((float)cr, (float)ci);
            double t = cr*cr - ci*ci; ci = 2.0*cr*ci; cr = t;
        }
    }

    // ---- intra-wave inclusive affine scan via shfl (no barriers) ----
    float2 v = make_float2(ur, ui);
    #pragma unroll
    for (int k = 0; k < 6; ++k) {
        const int off = 1 << k;
        float px = __shfl_up(v.x, off);
        float py = __shfl_up(v.y, off);
        if (lane >= off) v = cmadd(apow[k], make_float2(px, py), v);
    }
    // exclusive within wave
    float ex = __shfl_up(v.x, 1);
    float ey = __shfl_up(v.y, 1);
    float2 E = (lane == 0) ? make_float2(0.f, 0.f) : make_float2(ex, ey);

    // ---- cross-wave combine: 2 barriers total ----
    if (lane == 63) tb[wv] = v;          // wave totals
    __syncthreads();
    float2 P = make_float2(0.f, 0.f);    // carry entering this wave
    {
        float2 t0 = tb[0], t1 = tb[1], t2 = tb[2];
        if (wv >= 1) P = t0;
        if (wv >= 2) P = cmadd(apow[6], P, t1);   // apow[6] = (a^60)^64
        if (wv >= 3) P = cmadd(apow[6], P, t2);
    }
    __syncthreads();                     // totals region reused for staging

    // alpha^lane = (a^60)^lane via bits of lane
    float2 aL = make_float2(1.f, 0.f);
    #pragma unroll
    for (int k = 0; k < 6; ++k) {
        if ((lane >> k) & 1) {
            aL = make_float2(aL.x*apow[k].x - aL.y*apow[k].y,
                             aL.x*apow[k].y + aL.y*apow[k].x);
        }
    }
    const float2 us = cmadd(aL, P, E);   // u at this thread's segment start

    // ---- pass 2: recompute with correct u_start; stage tiles; drain coalesced ----
    const int  seg_lo = ws + tid * SEGS;
    const bool live   = (seg_lo + (SEGS - 1) >= wstart) && (seg_lo < wend);
    const int  sx     = tid & 15;        // write-side XOR swizzle key

    float pur = us.x, pui = us.y;
    float bre = b0re, bim = b0im;

    int row0 = tid / TILE;
    int k0   = tid - row0 * TILE;

    for (int h = 0; h < NTILES; ++h) {
        if (live) {
            #pragma unroll
            for (int k = 0; k < TILE; ++k) {
                float nr = fmaf(ar, pur, fmaf(-ai, pui, bre));
                float ni = fmaf(ar, pui, fmaf( ai, pur, bim));
                pur = nr; pui = ni;
                bre += dxs; bim += dys;
                tb[(tid << 4) + (k ^ sx)] = make_float2(nr, ni);
            }
        }
        __syncthreads();
        // drain 256*15 staged values; flat j = tid + 256*i  (256 = 17*15 + 1)
        {
            int row = row0, kk = k0;
            const int base = ws + h * TILE;
            #pragma unroll
            for (int i = 0; i < TILE; ++i) {
                float2 w = tb[(row << 4) + (kk ^ (row & 15))];
                const int o = base + row * SEGS + kk;     // model step index
                if (o >= wstart && o < wend) {
                    out[o + 1]        = w.x;   // real(U[o+1])
                    out[NTOT + o + 1] = w.y;   // imag(U[o+1])
                }
                row += 17; kk += 1;
                if (kk >= TILE) { kk -= TILE; row += 1; }
            }
        }
        __syncthreads();
    }

    // U[0] = 0
    if (blk == 0 && tid == 0) { out[0] = 0.f; out[NTOT] = 0.f; }
}

extern "C" void kernel_launch(void* const* d_in, const int* in_sizes, int n_in,
                              void* d_out, int out_size, void* d_ws, size_t ws_size,
                              hipStream_t stream)
{
    const float* pk  = (const float*)d_in[0];
    const float* TAx = (const float*)d_in[1];
    const float* TAy = (const float*)d_in[2];
    float* out = (float*)d_out;

    const int nblocks = (NSTEPS + CHUNK - 1) / CHUNK;   // 478
    slab_scan_kernel<<<dim3(nblocks), dim3(TPB), 0, stream>>>(pk, TAx, TAy, out);
}